// Round 6
// baseline (403.965 us; speedup 1.0000x reference)
//
#include <hip/hip_runtime.h>
#include <stdint.h>

// Tree-LSTM scan: B=256, L=128, STATE=128, INIT=256, Z=5*128=640. fp32 I/O.
// 16 blocks x 512 threads; block owns 16 batch rows; bf16 weights register-
// resident (160 VGPR/lane). LDS pushed past 80 KiB so only ONE workgroup fits
// per CU -> LDS-implied occupancy 2 waves/EU -> combined reg budget 256 ->
// weight array not spilled. (At 53.7 KB the LDS-implied target was 4 waves/EU
// -> budget 128 -> the weights spilled to scratch; L2 refill was the 330 us.)
// R5 lesson: a guarded plain store to the pad was DCE'd (LDS_Block_Size stayed
// 53760) -- this round the pad is kept alive with volatile accesses whose
// result escapes to global memory under an unprovable branch.

constexpr int kL      = 128;
constexpr int kState  = 128;
constexpr int kInit   = 256;
constexpr int kRows   = 16;
constexpr int kBlocks = 16;
constexpr int kThreads= 512;
constexpr int kHxStr  = 264;   // bf16 elems: [h 0:128 | x_rh 128:256 | pad 8]
constexpr int kXcStr  = 132;   // fp32 elems: right_c 128 + pad 4

typedef __attribute__((ext_vector_type(8))) short short8;    // MFMA A/B frag
typedef __attribute__((ext_vector_type(4))) short short4v;
typedef __attribute__((ext_vector_type(4))) float floatx4;   // MFMA C/D frag

__device__ __forceinline__ uint16_t f2bf(float f) {
    union { float f; uint32_t i; } v; v.f = f;
    return (uint16_t)((v.i + 0x7FFFu + ((v.i >> 16) & 1u)) >> 16);  // RNE
}
__device__ __forceinline__ short8 cvt8(const float* p) {
    float4 a = ((const float4*)p)[0];
    float4 b = ((const float4*)p)[1];
    short8 r;
    r[0]=f2bf(a.x); r[1]=f2bf(a.y); r[2]=f2bf(a.z); r[3]=f2bf(a.w);
    r[4]=f2bf(b.x); r[5]=f2bf(b.y); r[6]=f2bf(b.z); r[7]=f2bf(b.w);
    return r;
}
__device__ __forceinline__ float clampf(float x, float lo, float hi) {
    return fminf(fmaxf(x, lo), hi);
}

__global__ __launch_bounds__(kThreads)
__attribute__((amdgpu_waves_per_eu(2, 2)))
void tree_lstm_kernel(const int* __restrict__ ids,
                      const float* __restrict__ embed,
                      const float* __restrict__ whx_w,
                      const float* __restrict__ whx_b,
                      const float* __restrict__ init_state,
                      const float* __restrict__ final_w,
                      const float* __restrict__ final_b,
                      float* __restrict__ out)
{
    __shared__ alignas(16) uint16_t hx[2][kRows][kHxStr];  // bf16 [h | right_h]
    __shared__ alignas(16) float    xcf[2][kRows][kXcStr]; // fp32 right_c
    __shared__ int   ids_l[kRows * kL];
    __shared__ alignas(16) float bias_l[5 * kState];       // fp32 bias (640)
    __shared__ float hfin[kRows][kState + 4];              // fp32 final h
    __shared__ float partial[kRows][3][4];
    // Occupancy forcer: pushes LDS/block past 80 KiB so a second workgroup
    // cannot co-reside; LDS-implied occupancy becomes 2 waves/EU -> register
    // budget 256 -> the 160-VGPR weight array stays resident.
    __shared__ float lds_force_pad[8192];                  // 32 KiB

    const int tid  = threadIdx.x;
    const int w    = tid >> 6;        // wave 0..7 -> j-slice [16w,16w+16)
    const int lane = tid & 63;
    const int l15  = lane & 15;       // batch row (MFMA D col / B col)
    const int quad = lane >> 4;       // 0..3
    const int b0   = blockIdx.x * kRows;
    const int j0   = w * 16 + quad * 4;   // 4 consecutive j (MFMA D rows)
    const int row  = tid >> 5;        // staging: batch row 0..15
    const int c16  = tid & 31;        // staging: 8-elem chunk of 256-elem x row

    // Keep the pad alive: volatile store + volatile load escaping to global
    // memory, under a branch the compiler cannot prove dead (ids >= 0 always).
    if (__builtin_expect(ids[0] < 0, 0)) {
        volatile float* vp = lds_force_pad;
        vp[tid] = (float)tid;
        float v = vp[(tid * 7) & 8191];
        if (v < -1.0e30f) out[0] = v;
    }

    // ids -> LDS, coalesced
    ((int4*)ids_l)[tid] = ((const int4*)(ids + b0 * kL))[tid];
    // bias -> LDS. 640 elements, 512 threads: two strided writes.
    bias_l[tid] = whx_b[tid];
    if (tid < 5 * kState - kThreads) bias_l[kThreads + tid] = whx_b[kThreads + tid];

    // register-resident A-frags of z^T = W * hx^T (fp32 -> bf16 RNE)
    // A layout: m = lane&15 (W row n0+l15), k = kk*32 + quad*8 + [0..8)
    short8 wf[5][8];
#pragma unroll
    for (int g = 0; g < 5; ++g) {
        const float* wrow = whx_w + (size_t)(g * 128 + w * 16 + l15) * kInit;
#pragma unroll
        for (int kk = 0; kk < 8; ++kk)
            wf[g][kk] = cvt8(wrow + kk * 32 + quad * 8);
    }

    // init h0 (bf16 -> LDS) and c0 (fp32 registers), broadcast over batch
    float c_reg[4];
    {
        uint16_t h0[4];
#pragma unroll
        for (int r = 0; r < 4; ++r) {
            h0[r]    = f2bf(init_state[j0 + r]);
            c_reg[r] = init_state[128 + j0 + r];
        }
        *(short4v*)&hx[0][l15][j0] = *(short4v*)h0;
    }
    __syncthreads();   // ids_l + bias + h0 visible

    // stage x[:,0] into buffer 0
    {
        int id = ids_l[row * kL];
        const float* erow = embed + (size_t)id * kInit + c16 * 8;
        if (c16 < 16) *(short8*)&hx[0][row][128 + c16 * 8] = cvt8(erow);
        else {
            ((float4*)&xcf[0][row][(c16 - 16) * 8])[0] = ((const float4*)erow)[0];
            ((float4*)&xcf[0][row][(c16 - 16) * 8])[1] = ((const float4*)erow)[1];
        }
    }
    __syncthreads();

    const float K1 = 1.442695041f;   // log2(e)
    const float K2 = 2.885390082f;   // 2*log2(e)

    for (int t = 0; t < kL; ++t) {
        const int cur = t & 1, nxt = cur ^ 1;

        // prefetch x[:, t+1] (global load latency hidden under K-loop)
        const int tn = (t + 1 < kL) ? t + 1 : kL - 1;
        int id = ids_l[row * kL + tn];
        const float* erow = embed + (size_t)id * kInit + c16 * 8;
        float4 xa = ((const float4*)erow)[0];
        float4 xb = ((const float4*)erow)[1];

        // acc init = bias (b128 broadcast reads: 16 lanes/quad same address)
        floatx4 acc[5];
#pragma unroll
        for (int g = 0; g < 5; ++g)
            acc[g] = *(const floatx4*)&bias_l[g * 128 + j0];

        // K-loop: z^T 16x16 tiles
        const uint16_t* hxr = &hx[cur][l15][0];
#pragma unroll
        for (int kk = 0; kk < 8; ++kk) {
            short8 xf = *(const short8*)(hxr + kk * 32 + quad * 8);  // B frag
#pragma unroll
            for (int g = 0; g < 5; ++g)
                acc[g] = __builtin_amdgcn_mfma_f32_16x16x32_bf16(wf[g][kk], xf, acc[g], 0, 0, 0);
        }

        // staged x -> next buffers (disjoint from hx[cur] reads & h writes)
        if (c16 < 16) {
            uint16_t xv[8];
            xv[0]=f2bf(xa.x); xv[1]=f2bf(xa.y); xv[2]=f2bf(xa.z); xv[3]=f2bf(xa.w);
            xv[4]=f2bf(xb.x); xv[5]=f2bf(xb.y); xv[6]=f2bf(xb.z); xv[7]=f2bf(xb.w);
            *(short8*)&hx[nxt][row][128 + c16 * 8] = *(short8*)xv;
        } else {
            ((float4*)&xcf[nxt][row][(c16 - 16) * 8])[0] = xa;
            ((float4*)&xcf[nxt][row][(c16 - 16) * 8])[1] = xb;
        }

        // gates: lane owns (b=l15, j=j0..j0+3); all 5 gates in acc[g][r]
        floatx4 rcv = *(const floatx4*)&xcf[cur][l15][j0];
        uint16_t hv[4];
        float hf[4];
#pragma unroll
        for (int r = 0; r < 4; ++r) {
            float a  = clampf(acc[0][r], -15.f, 15.f);
            float ii = clampf(acc[1][r], -30.f, 30.f);
            float f1 = clampf(acc[2][r], -30.f, 30.f);
            float f2 = clampf(acc[3][r], -30.f, 30.f);
            float oo = clampf(acc[4][r], -30.f, 30.f);

            // tanh(a)*sigmoid(i), one rcp
            float Ea = exp2f(a * K2);                 // e^{2a}  <= 2^43.3
            float Ei = exp2f(-ii * K1);               // e^{-i}  <= 2^43.3
            float P  = (Ea - 1.0f) * __builtin_amdgcn_rcpf((Ea + 1.0f) * (1.0f + Ei));
            // sigmoid(f1)*lc + sigmoid(f2)*rc, one rcp
            float E1 = exp2f(f1 * K1), E2 = exp2f(f2 * K1);   // <= 2^43.3
            float lc = c_reg[r], rc = rcv[r];
            float num = E1 * (1.0f + E2) * lc + E2 * (1.0f + E1) * rc;
            float Q  = num * __builtin_amdgcn_rcpf((1.0f + E1) * (1.0f + E2));
            float c  = P + Q;
            c_reg[r] = c;
            // sigmoid(o)*tanh(c), one rcp
            float Eo = exp2f(-oo * K1);
            float cc = clampf(c, -15.f, 15.f);
            float Ec = exp2f(cc * K2);
            float h  = (Ec - 1.0f) * __builtin_amdgcn_rcpf((1.0f + Eo) * (Ec + 1.0f));
            hv[r] = f2bf(h);
            hf[r] = h;
        }
        *(short4v*)&hx[nxt][l15][j0] = *(short4v*)hv;
        if (t == kL - 1) {
#pragma unroll
            for (int r = 0; r < 4; ++r) hfin[l15][j0 + r] = hf[r];
        }
        __syncthreads();
    }

    // final: out[b][o] = sum_j hfin[b][j]*final_w[o][j] + final_b[o]
    if (tid < 192) {
        int b = tid / 12, rem = tid % 12;
        int o = rem >> 2, q4 = rem & 3;
        float s = 0.f;
        const float* wrow = final_w + o * kState;
#pragma unroll 8
        for (int j = q4 * 32; j < q4 * 32 + 32; ++j)
            s += hfin[b][j] * wrow[j];
        partial[b][o][q4] = s;
    }
    __syncthreads();
    if (tid < 48) {
        int b = tid / 3, o = tid % 3;
        float s = partial[b][o][0] + partial[b][o][1] +
                  partial[b][o][2] + partial[b][o][3] + final_b[o];
        out[(b0 + b) * 3 + o] = s;
    }
}

extern "C" void kernel_launch(void* const* d_in, const int* in_sizes, int n_in,
                              void* d_out, int out_size, void* d_ws, size_t ws_size,
                              hipStream_t stream) {
    const int*   ids        = (const int*)d_in[0];
    const float* embed      = (const float*)d_in[1];
    const float* whx_w      = (const float*)d_in[2];
    const float* whx_b      = (const float*)d_in[3];
    const float* init_state = (const float*)d_in[4];
    const float* final_w    = (const float*)d_in[5];
    const float* final_b    = (const float*)d_in[6];
    float*       out        = (float*)d_out;
    hipLaunchKernelGGL(tree_lstm_kernel, dim3(kBlocks), dim3(kThreads), 0, stream,
                       ids, embed, whx_w, whx_b, init_state, final_w, final_b, out);
}

// Round 7
// 368.041 us; speedup vs baseline: 1.0976x; 1.0976x over previous
//
#include <hip/hip_runtime.h>
#include <stdint.h>

// Tree-LSTM scan: B=256, L=128, STATE=128, INIT=256, Z=5*128=640. fp32 I/O.
// 16 blocks x 512 threads; block owns 16 batch rows; bf16 weights register-
// resident (160 VGPR/lane; gfx950 unified VGPR+AGPR budget = 256/lane at
// 8 waves/CU). R2-R6 spilled ~40 regs/thread because peak pressure (~290)
// exceeded 256: wf(160)+acc(20)+hoisted B-frags+embed prefetch regs+staging
// temps. This version moves the embed prefetch to LDS via
// global_load_lds (zero VGPRs), reads right_c straight from the fp32 staging
// buffer, deletes the fp32 final-h path, and pins the t-loop to unroll 1.
// Peak pressure ~230 < 256 -> no spill.

constexpr int kL      = 128;
constexpr int kState  = 128;
constexpr int kInit   = 256;
constexpr int kRows   = 16;
constexpr int kBlocks = 16;
constexpr int kThreads= 512;
constexpr int kHxStr  = 264;   // bf16 elems: [h 0:128 | x_rh 128:256 | pad 8]
constexpr int kXsStr  = 260;   // fp32 elems: embed row 256 + pad 4 (bank decorrelate)

typedef __attribute__((ext_vector_type(8))) short short8;    // MFMA A/B frag
typedef __attribute__((ext_vector_type(4))) short short4v;
typedef __attribute__((ext_vector_type(4))) float floatx4;   // MFMA C/D frag

__device__ __forceinline__ uint16_t f2bf(float f) {
    union { float f; uint32_t i; } v; v.f = f;
    return (uint16_t)((v.i + 0x7FFFu + ((v.i >> 16) & 1u)) >> 16);  // RNE
}
__device__ __forceinline__ float bf2f(uint16_t u) {
    union { uint32_t i; float f; } v; v.i = ((uint32_t)u) << 16; return v.f;
}
__device__ __forceinline__ short8 cvt8(const float* p) {
    float4 a = ((const float4*)p)[0];
    float4 b = ((const float4*)p)[1];
    short8 r;
    r[0]=f2bf(a.x); r[1]=f2bf(a.y); r[2]=f2bf(a.z); r[3]=f2bf(a.w);
    r[4]=f2bf(b.x); r[5]=f2bf(b.y); r[6]=f2bf(b.z); r[7]=f2bf(b.w);
    return r;
}
__device__ __forceinline__ float clampf(float x, float lo, float hi) {
    return fminf(fmaxf(x, lo), hi);
}
// Async global -> LDS, 16 B/lane. LDS dest = wave-uniform base + lane*16;
// global src = per-lane address. (learn_hip m03/m97/m104 semantics.)
__device__ __forceinline__ void gload_lds16(const float* g, float* l) {
    __builtin_amdgcn_global_load_lds(
        (const __attribute__((address_space(1))) uint32_t*)(uintptr_t)g,
        (__attribute__((address_space(3))) uint32_t*)(uintptr_t)l, 16, 0, 0);
}

__global__ __launch_bounds__(kThreads)
__attribute__((amdgpu_waves_per_eu(1, 2)))
void tree_lstm_kernel(const int* __restrict__ ids,
                      const float* __restrict__ embed,
                      const float* __restrict__ whx_w,
                      const float* __restrict__ whx_b,
                      const float* __restrict__ init_state,
                      const float* __restrict__ final_w,
                      const float* __restrict__ final_b,
                      float* __restrict__ out)
{
    __shared__ alignas(16) uint16_t hx[2][kRows][kHxStr];   // bf16 [h | right_h]
    __shared__ alignas(16) float    xstg[2][kRows][kXsStr]; // fp32 raw embed rows
    __shared__ int   ids_l[kRows * kL];
    __shared__ alignas(16) float bias_l[5 * kState];        // fp32 bias (640)
    __shared__ float partial[kRows][3][4];
    // Keep LDS > 80 KiB: guarantees 1 workgroup/CU (8 waves/CU) regardless of
    // scheduler heuristics. Kept alive with volatile accesses under an
    // unprovable branch (proven to materialize in R6: LDS_Block_Size 86528).
    __shared__ float lds_force_pad[6144];                   // 24 KiB

    const int tid  = threadIdx.x;
    const int w    = tid >> 6;        // wave 0..7 -> j-slice [16w,16w+16)
    const int lane = tid & 63;
    const int l15  = lane & 15;       // batch row (MFMA D col / B col)
    const int quad = lane >> 4;       // 0..3
    const int b0   = blockIdx.x * kRows;
    const int j0   = w * 16 + quad * 4;   // 4 consecutive j (MFMA D rows)
    const int row  = tid >> 5;        // convert pass: batch row 0..15
    const int c16  = tid & 31;        // convert pass: 4-float chunk (cols 4c16..+4)

    if (__builtin_expect(ids[0] < 0, 0)) {      // never true; keeps pad alive
        volatile float* vp = lds_force_pad;
        vp[tid] = (float)tid;
        float v = vp[(tid * 7) & 6143];
        if (v < -1.0e30f) out[0] = v;
    }

    // ids -> LDS, coalesced. Wave w writes int4 indices 64w..64w+63, which is
    // exactly rows 2w,2w+1 -- the rows wave w later reads (same-wave ordering).
    ((int4*)ids_l)[tid] = ((const int4*)(ids + b0 * kL))[tid];
    // bias -> LDS (640 elems, 512 threads)
    bias_l[tid] = whx_b[tid];
    if (tid < 5 * kState - kThreads) bias_l[kThreads + tid] = whx_b[kThreads + tid];

    // register-resident A-frags of z^T = W * hx^T (fp32 -> bf16 RNE)
    // A layout: m = lane&15 (W row n0+l15), k = kk*32 + quad*8 + [0..8)
    short8 wf[5][8];
#pragma unroll
    for (int g = 0; g < 5; ++g) {
        const float* wrow = whx_w + (size_t)(g * 128 + w * 16 + l15) * kInit;
#pragma unroll
        for (int kk = 0; kk < 8; ++kk)
            wf[g][kk] = cvt8(wrow + kk * 32 + quad * 8);
    }

    // init h0 (bf16 -> LDS) and c0 (fp32 registers), broadcast over batch
    float c_reg[4];
    {
        uint16_t h0[4];
#pragma unroll
        for (int r = 0; r < 4; ++r) {
            h0[r]    = f2bf(init_state[j0 + r]);
            c_reg[r] = init_state[128 + j0 + r];
        }
        *(short4v*)&hx[0][l15][j0] = *(short4v*)h0;
    }

    // issue async loads of x(:,0) -> xstg[0] (wave w: rows 2w, 2w+1)
    {
        int idA = ids_l[(2 * w) * kL];
        int idB = ids_l[(2 * w + 1) * kL];
        gload_lds16(embed + (size_t)idA * kInit + lane * 4, &xstg[0][2 * w][0]);
        gload_lds16(embed + (size_t)idB * kInit + lane * 4, &xstg[0][2 * w + 1][0]);
    }
    __syncthreads();   // drains vmcnt (xstg[0] complete) + ids/bias/h0 visible
    // convert x(:,0) right_h fp32 -> bf16 into hx[0]
    {
        float4 v = *(const float4*)&xstg[0][row][c16 * 4];
        uint16_t o4[4] = { f2bf(v.x), f2bf(v.y), f2bf(v.z), f2bf(v.w) };
        *(short4v*)&hx[0][row][128 + c16 * 4] = *(short4v*)o4;
    }
    __syncthreads();

    const float K1 = 1.442695041f;   // log2(e)
    const float K2 = 2.885390082f;   // 2*log2(e)

#pragma unroll 1
    for (int t = 0; t < kL; ++t) {
        const int cur = t & 1, nxt = cur ^ 1;

        // async prefetch x(:, t+1) -> xstg[nxt]; zero VGPR cost, consumed
        // after barrier1 (auto vmcnt(0) drain) in the convert pass below.
        const int tn = (t + 1 < kL) ? t + 1 : kL - 1;
        {
            int idA = ids_l[(2 * w) * kL + tn];
            int idB = ids_l[(2 * w + 1) * kL + tn];
            gload_lds16(embed + (size_t)idA * kInit + lane * 4, &xstg[nxt][2 * w][0]);
            gload_lds16(embed + (size_t)idB * kInit + lane * 4, &xstg[nxt][2 * w + 1][0]);
        }

        // acc init = bias (b128 broadcast reads)
        floatx4 acc[5];
#pragma unroll
        for (int g = 0; g < 5; ++g)
            acc[g] = *(const floatx4*)&bias_l[g * 128 + j0];

        // K-loop: z^T 16x16 tiles
        const uint16_t* hxr = &hx[cur][l15][0];
#pragma unroll
        for (int kk = 0; kk < 8; ++kk) {
            short8 xf = *(const short8*)(hxr + kk * 32 + quad * 8);  // B frag
#pragma unroll
            for (int g = 0; g < 5; ++g)
                acc[g] = __builtin_amdgcn_mfma_f32_16x16x32_bf16(wf[g][kk], xf, acc[g], 0, 0, 0);
        }

        // gates: lane owns (b=l15, j=j0..j0+3); right_c straight from fp32 stage
        floatx4 rcv = *(const floatx4*)&xstg[cur][l15][128 + j0];
        uint16_t hv[4];
#pragma unroll
        for (int r = 0; r < 4; ++r) {
            float a  = clampf(acc[0][r], -15.f, 15.f);
            float ii = clampf(acc[1][r], -30.f, 30.f);
            float f1 = clampf(acc[2][r], -30.f, 30.f);
            float f2 = clampf(acc[3][r], -30.f, 30.f);
            float oo = clampf(acc[4][r], -30.f, 30.f);

            // tanh(a)*sigmoid(i), one rcp
            float Ea = exp2f(a * K2);                 // e^{2a}  <= 2^43.3
            float Ei = exp2f(-ii * K1);               // e^{-i}  <= 2^43.3
            float P  = (Ea - 1.0f) * __builtin_amdgcn_rcpf((Ea + 1.0f) * (1.0f + Ei));
            // sigmoid(f1)*lc + sigmoid(f2)*rc, one rcp
            float E1 = exp2f(f1 * K1), E2 = exp2f(f2 * K1);
            float lc = c_reg[r], rc = rcv[r];
            float num = E1 * (1.0f + E2) * lc + E2 * (1.0f + E1) * rc;
            float Q  = num * __builtin_amdgcn_rcpf((1.0f + E1) * (1.0f + E2));
            float c  = P + Q;
            c_reg[r] = c;
            // sigmoid(o)*tanh(c), one rcp
            float Eo = exp2f(-oo * K1);
            float cc = clampf(c, -15.f, 15.f);
            float Ec = exp2f(cc * K2);
            float h  = (Ec - 1.0f) * __builtin_amdgcn_rcpf((1.0f + Eo) * (Ec + 1.0f));
            hv[r] = f2bf(h);
        }
        *(short4v*)&hx[nxt][l15][j0] = *(short4v*)hv;

        __syncthreads();   // barrier1: drains global_load_lds; h-writes visible
        // convert x(:, t+1) right_h fp32 -> bf16 into hx[nxt] (regs are free here)
        {
            float4 v = *(const float4*)&xstg[nxt][row][c16 * 4];
            uint16_t o4[4] = { f2bf(v.x), f2bf(v.y), f2bf(v.z), f2bf(v.w) };
            *(short4v*)&hx[nxt][row][128 + c16 * 4] = *(short4v*)o4;
        }
        __syncthreads();   // barrier2: converted x visible for next K-loop
    }

    // final: out[b][o] = sum_j h[b][j]*final_w[o][j] + final_b[o]
    // h(final) is bf16 in hx[0] (t=127 wrote nxt=0); bf16 h error ~4e-3 rel.
    if (tid < 192) {
        int b = tid / 12, rem = tid % 12;
        int o = rem >> 2, q4 = rem & 3;
        float s = 0.f;
        const uint16_t* hrow = &hx[0][b][0];
        const float* wrow = final_w + o * kState;
#pragma unroll 8
        for (int j = q4 * 32; j < q4 * 32 + 32; ++j)
            s += bf2f(hrow[j]) * wrow[j];
        partial[b][o][q4] = s;
    }
    __syncthreads();
    if (tid < 48) {
        int b = tid / 3, o = tid % 3;
        float s = partial[b][o][0] + partial[b][o][1] +
                  partial[b][o][2] + partial[b][o][3] + final_b[o];
        out[(b0 + b) * 3 + o] = s;
    }
}

extern "C" void kernel_launch(void* const* d_in, const int* in_sizes, int n_in,
                              void* d_out, int out_size, void* d_ws, size_t ws_size,
                              hipStream_t stream) {
    const int*   ids        = (const int*)d_in[0];
    const float* embed      = (const float*)d_in[1];
    const float* whx_w      = (const float*)d_in[2];
    const float* whx_b      = (const float*)d_in[3];
    const float* init_state = (const float*)d_in[4];
    const float* final_w    = (const float*)d_in[5];
    const float* final_b    = (const float*)d_in[6];
    float*       out        = (float*)d_out;
    hipLaunchKernelGGL(tree_lstm_kernel, dim3(kBlocks), dim3(kThreads), 0, stream,
                       ids, embed, whx_w, whx_b, init_state, final_w, final_b, out);
}

// Round 8
// 340.029 us; speedup vs baseline: 1.1880x; 1.0824x over previous
//
#include <hip/hip_runtime.h>
#include <stdint.h>

// Tree-LSTM scan: B=256, L=128, STATE=128, INIT=256, Z=5*128=640. fp32 I/O.
// Two kernels: (1) convert whx_w fp32->bf16 into d_ws; (2) scan kernel with
// 16 blocks x 512 threads, block owns 16 batch rows, bf16 weights register-
// resident (160 VGPR/lane within the 256 unified VGPR+AGPR budget at 8
// waves/CU). R7 lesson: loading fp32 weights + converting in the prologue
// spiked pressure past 256 while *defining* wf -> ~86 regs of wf spilled to
// scratch and were refilled from L2 every step (the 284 us). Loading
// pre-converted bf16 puts each global_load_dwordx4 result directly in its
// final wf register: no staging temps, no spike, no spill.

constexpr int kL      = 128;
constexpr int kState  = 128;
constexpr int kInit   = 256;
constexpr int kRows   = 16;
constexpr int kBlocks = 16;
constexpr int kThreads= 512;
constexpr int kHxStr  = 264;   // bf16 elems: [h 0:128 | x_rh 128:256 | pad 8]
constexpr int kXsStr  = 260;   // fp32 elems: embed row 256 + pad 4
constexpr int kWElems = 5 * kState * kInit;   // 163840 weight elements

typedef __attribute__((ext_vector_type(8))) short short8;    // MFMA A/B frag
typedef __attribute__((ext_vector_type(4))) short short4v;
typedef __attribute__((ext_vector_type(4))) float floatx4;   // MFMA C/D frag

__device__ __forceinline__ uint16_t f2bf(float f) {
    union { float f; uint32_t i; } v; v.f = f;
    return (uint16_t)((v.i + 0x7FFFu + ((v.i >> 16) & 1u)) >> 16);  // RNE
}
__device__ __forceinline__ float bf2f(uint16_t u) {
    union { uint32_t i; float f; } v; v.i = ((uint32_t)u) << 16; return v.f;
}
__device__ __forceinline__ float clampf(float x, float lo, float hi) {
    return fminf(fmaxf(x, lo), hi);
}
// Async global -> LDS, 16 B/lane. LDS dest = wave-uniform base + lane*16.
__device__ __forceinline__ void gload_lds16(const float* g, float* l) {
    __builtin_amdgcn_global_load_lds(
        (const __attribute__((address_space(1))) uint32_t*)(uintptr_t)g,
        (__attribute__((address_space(3))) uint32_t*)(uintptr_t)l, 16, 0, 0);
}

// ---- kernel 1: whx_w fp32 -> bf16 (row-major 640x256) into d_ws ----
__global__ __launch_bounds__(256)
void convert_weights_kernel(const float* __restrict__ wsrc,
                            uint16_t* __restrict__ wdst) {
    int i = blockIdx.x * 256 + threadIdx.x;          // float4 index
    float4 v = ((const float4*)wsrc)[i];
    uint16_t q[4] = { f2bf(v.x), f2bf(v.y), f2bf(v.z), f2bf(v.w) };
    ((short4v*)wdst)[i] = *(short4v*)q;
}

// ---- kernel 2: the scan ----
__global__ __launch_bounds__(kThreads)
__attribute__((amdgpu_waves_per_eu(1, 2)))
void tree_lstm_kernel(const int* __restrict__ ids,
                      const float* __restrict__ embed,
                      const uint16_t* __restrict__ wbf,   // pre-converted bf16 W
                      const float* __restrict__ whx_b,
                      const float* __restrict__ init_state,
                      const float* __restrict__ final_w,
                      const float* __restrict__ final_b,
                      float* __restrict__ out)
{
    __shared__ alignas(16) uint16_t hx[2][kRows][kHxStr];   // bf16 [h | right_h]
    __shared__ alignas(16) float    xstg[2][kRows][kXsStr]; // fp32 raw embed rows
    __shared__ int   ids_l[kRows * kL];
    __shared__ alignas(16) float bias_l[5 * kState];        // fp32 bias (640)
    __shared__ float partial[kRows][3][4];
    // Keep LDS > 80 KiB: exactly 1 workgroup/CU (blocks spread over 16 CUs,
    // LDS-implied occupancy 2 waves/EU). Kept alive via volatile accesses
    // under an unprovable branch (materialization proven in R6).
    __shared__ float lds_force_pad[6144];                   // 24 KiB

    const int tid  = threadIdx.x;
    const int w    = tid >> 6;        // wave 0..7 -> j-slice [16w,16w+16)
    const int lane = tid & 63;
    const int l15  = lane & 15;       // batch row (MFMA D col / B col)
    const int quad = lane >> 4;       // 0..3
    const int b0   = blockIdx.x * kRows;
    const int j0   = w * 16 + quad * 4;   // 4 consecutive j (MFMA D rows)
    const int row  = tid >> 5;        // convert pass: batch row 0..15
    const int c16  = tid & 31;        // convert pass: 4-float chunk

    if (__builtin_expect(ids[0] < 0, 0)) {      // never true; keeps pad alive
        volatile float* vp = lds_force_pad;
        vp[tid] = (float)tid;
        float v = vp[(tid * 7) & 6143];
        if (v < -1.0e30f) out[0] = v;
    }

    // ids -> LDS, coalesced (wave w writes exactly rows 2w,2w+1 it later reads)
    ((int4*)ids_l)[tid] = ((const int4*)(ids + b0 * kL))[tid];
    // bias -> LDS (640 elems, 512 threads)
    bias_l[tid] = whx_b[tid];
    if (tid < 5 * kState - kThreads) bias_l[kThreads + tid] = whx_b[kThreads + tid];

    // register-resident A-frags of z^T = W * hx^T, loaded DIRECTLY as bf16:
    // one global_load_dwordx4 per fragment, dest = final wf register.
    // A layout: m = lane&15 (W row g*128 + w*16 + l15), k = kk*32+quad*8+[0..8)
    short8 wf[5][8];
#pragma unroll
    for (int g = 0; g < 5; ++g) {
        const uint16_t* wrow = wbf + (size_t)(g * 128 + w * 16 + l15) * kInit;
#pragma unroll
        for (int kk = 0; kk < 8; ++kk)
            wf[g][kk] = *(const short8*)(wrow + kk * 32 + quad * 8);
    }

    // init h0 (bf16 -> LDS) and c0 (fp32 registers), broadcast over batch
    float c_reg[4];
    {
        uint16_t h0[4];
#pragma unroll
        for (int r = 0; r < 4; ++r) {
            h0[r]    = f2bf(init_state[j0 + r]);
            c_reg[r] = init_state[128 + j0 + r];
        }
        *(short4v*)&hx[0][l15][j0] = *(short4v*)h0;
    }

    // issue async loads of x(:,0) -> xstg[0] (wave w: rows 2w, 2w+1)
    {
        int idA = ids_l[(2 * w) * kL];
        int idB = ids_l[(2 * w + 1) * kL];
        gload_lds16(embed + (size_t)idA * kInit + lane * 4, &xstg[0][2 * w][0]);
        gload_lds16(embed + (size_t)idB * kInit + lane * 4, &xstg[0][2 * w + 1][0]);
    }
    __syncthreads();   // drains vmcnt (xstg[0] complete) + ids/bias/h0 visible
    // convert x(:,0) right_h fp32 -> bf16 into hx[0]
    {
        float4 v = *(const float4*)&xstg[0][row][c16 * 4];
        uint16_t o4[4] = { f2bf(v.x), f2bf(v.y), f2bf(v.z), f2bf(v.w) };
        *(short4v*)&hx[0][row][128 + c16 * 4] = *(short4v*)o4;
    }
    __syncthreads();

    const float K1 = 1.442695041f;   // log2(e)
    const float K2 = 2.885390082f;   // 2*log2(e)

#pragma unroll 1
    for (int t = 0; t < kL; ++t) {
        const int cur = t & 1, nxt = cur ^ 1;

        // async prefetch x(:, t+1) -> xstg[nxt]; zero VGPR cost
        const int tn = (t + 1 < kL) ? t + 1 : kL - 1;
        {
            int idA = ids_l[(2 * w) * kL + tn];
            int idB = ids_l[(2 * w + 1) * kL + tn];
            gload_lds16(embed + (size_t)idA * kInit + lane * 4, &xstg[nxt][2 * w][0]);
            gload_lds16(embed + (size_t)idB * kInit + lane * 4, &xstg[nxt][2 * w + 1][0]);
        }

        // acc init = bias (b128 broadcast reads)
        floatx4 acc[5];
#pragma unroll
        for (int g = 0; g < 5; ++g)
            acc[g] = *(const floatx4*)&bias_l[g * 128 + j0];

        // K-loop: z^T 16x16 tiles
        const uint16_t* hxr = &hx[cur][l15][0];
#pragma unroll
        for (int kk = 0; kk < 8; ++kk) {
            short8 xf = *(const short8*)(hxr + kk * 32 + quad * 8);  // B frag
#pragma unroll
            for (int g = 0; g < 5; ++g)
                acc[g] = __builtin_amdgcn_mfma_f32_16x16x32_bf16(wf[g][kk], xf, acc[g], 0, 0, 0);
        }

        // gates: lane owns (b=l15, j=j0..j0+3); right_c straight from fp32 stage
        floatx4 rcv = *(const floatx4*)&xstg[cur][l15][128 + j0];
        uint16_t hv[4];
#pragma unroll
        for (int r = 0; r < 4; ++r) {
            float a  = clampf(acc[0][r], -15.f, 15.f);
            float ii = clampf(acc[1][r], -30.f, 30.f);
            float f1 = clampf(acc[2][r], -30.f, 30.f);
            float f2 = clampf(acc[3][r], -30.f, 30.f);
            float oo = clampf(acc[4][r], -30.f, 30.f);

            // tanh(a)*sigmoid(i), one rcp
            float Ea = exp2f(a * K2);
            float Ei = exp2f(-ii * K1);
            float P  = (Ea - 1.0f) * __builtin_amdgcn_rcpf((Ea + 1.0f) * (1.0f + Ei));
            // sigmoid(f1)*lc + sigmoid(f2)*rc, one rcp
            float E1 = exp2f(f1 * K1), E2 = exp2f(f2 * K1);
            float lc = c_reg[r], rc = rcv[r];
            float num = E1 * (1.0f + E2) * lc + E2 * (1.0f + E1) * rc;
            float Q  = num * __builtin_amdgcn_rcpf((1.0f + E1) * (1.0f + E2));
            float c  = P + Q;
            c_reg[r] = c;
            // sigmoid(o)*tanh(c), one rcp
            float Eo = exp2f(-oo * K1);
            float cc = clampf(c, -15.f, 15.f);
            float Ec = exp2f(cc * K2);
            float h  = (Ec - 1.0f) * __builtin_amdgcn_rcpf((1.0f + Eo) * (Ec + 1.0f));
            hv[r] = f2bf(h);
        }
        *(short4v*)&hx[nxt][l15][j0] = *(short4v*)hv;

        __syncthreads();   // barrier1: drains global_load_lds; h-writes visible
        // convert x(:, t+1) right_h fp32 -> bf16 into hx[nxt]
        {
            float4 v = *(const float4*)&xstg[nxt][row][c16 * 4];
            uint16_t o4[4] = { f2bf(v.x), f2bf(v.y), f2bf(v.z), f2bf(v.w) };
            *(short4v*)&hx[nxt][row][128 + c16 * 4] = *(short4v*)o4;
        }
        __syncthreads();   // barrier2: converted x visible for next K-loop
    }

    // final: out[b][o] = sum_j h[b][j]*final_w[o][j] + final_b[o]
    if (tid < 192) {
        int b = tid / 12, rem = tid % 12;
        int o = rem >> 2, q4 = rem & 3;
        float s = 0.f;
        const uint16_t* hrow = &hx[0][b][0];
        const float* wrow = final_w + o * kState;
#pragma unroll 8
        for (int j = q4 * 32; j < q4 * 32 + 32; ++j)
            s += bf2f(hrow[j]) * wrow[j];
        partial[b][o][q4] = s;
    }
    __syncthreads();
    if (tid < 48) {
        int b = tid / 3, o = tid % 3;
        float s = partial[b][o][0] + partial[b][o][1] +
                  partial[b][o][2] + partial[b][o][3] + final_b[o];
        out[(b0 + b) * 3 + o] = s;
    }
}

extern "C" void kernel_launch(void* const* d_in, const int* in_sizes, int n_in,
                              void* d_out, int out_size, void* d_ws, size_t ws_size,
                              hipStream_t stream) {
    const int*   ids        = (const int*)d_in[0];
    const float* embed      = (const float*)d_in[1];
    const float* whx_w      = (const float*)d_in[2];
    const float* whx_b      = (const float*)d_in[3];
    const float* init_state = (const float*)d_in[4];
    const float* final_w    = (const float*)d_in[5];
    const float* final_b    = (const float*)d_in[6];
    float*       out        = (float*)d_out;
    uint16_t*    wbf        = (uint16_t*)d_ws;   // 640*256*2 = 320 KiB

    convert_weights_kernel<<<kWElems / 4 / 256, 256, 0, stream>>>(whx_w, wbf);
    tree_lstm_kernel<<<kBlocks, kThreads, 0, stream>>>(
        ids, embed, wbf, whx_b, init_state, final_w, final_b, out);
}

// Round 9
// 327.760 us; speedup vs baseline: 1.2325x; 1.0374x over previous
//
#include <hip/hip_runtime.h>
#include <stdint.h>

// Tree-LSTM scan: B=256, L=128, STATE=128, INIT=256, Z=5*128=640. fp32 I/O.
// Pipeline: (0) whx_w fp32->bf16 into d_ws; (1) gather embed[ids] ->
// xbf[b][t][256] bf16, XOR-swizzled (full-GPU-width gather); (2) scan kernel:
// 16 blocks x 512 threads, weights register-resident (WRITE_SIZE=3KB proven
// in R8), ONE barrier/step, all LDS accesses 2-way-conflict-free via
// slot = chunk ^ row swizzle (global_load_lds requires contiguous dest, so
// swizzle is baked into xbf's global layout by kernel 1).

constexpr int kL      = 128;
constexpr int kState  = 128;
constexpr int kInit   = 256;
constexpr int kRows   = 16;
constexpr int kBlocks = 16;
constexpr int kThreads= 512;
constexpr int kWElems = 5 * kState * kInit;     // 163840 (320 KiB bf16)
constexpr int kXRows  = 256 * kL;               // 32768 (b,t) rows

typedef __attribute__((ext_vector_type(8))) short short8;    // MFMA A/B frag
typedef __attribute__((ext_vector_type(4))) short short4v;
typedef __attribute__((ext_vector_type(4))) float floatx4;   // MFMA C/D frag

__device__ __forceinline__ uint16_t f2bf(float f) {
    union { float f; uint32_t i; } v; v.f = f;
    return (uint16_t)((v.i + 0x7FFFu + ((v.i >> 16) & 1u)) >> 16);  // RNE
}
__device__ __forceinline__ float bf2f(uint16_t u) {
    union { uint32_t i; float f; } v; v.i = ((uint32_t)u) << 16; return v.f;
}
__device__ __forceinline__ float clampf(float x, float lo, float hi) {
    return fminf(fmaxf(x, lo), hi);
}
// Async global -> LDS, 16 B/lane. LDS dest = wave-uniform base + lane*16.
__device__ __forceinline__ void gload_lds16(const void* g, void* l) {
    __builtin_amdgcn_global_load_lds(
        (const __attribute__((address_space(1))) uint32_t*)(uintptr_t)g,
        (__attribute__((address_space(3))) uint32_t*)(uintptr_t)l, 16, 0, 0);
}

// ---- kernel 0: whx_w fp32 -> bf16 (row-major 640x256) ----
__global__ __launch_bounds__(256)
void convert_weights_kernel(const float* __restrict__ wsrc,
                            uint16_t* __restrict__ wdst) {
    int i = blockIdx.x * 256 + threadIdx.x;          // float4 index
    float4 v = ((const float4*)wsrc)[i];
    uint16_t q[4] = { f2bf(v.x), f2bf(v.y), f2bf(v.z), f2bf(v.w) };
    ((short4v*)wdst)[i] = *(short4v*)q;
}

// ---- kernel 1: xbf[b*128+t][slot] = bf16(embed[ids[b][t]][chunk]) ----
// slot = chunk ^ (b & 15): the LDS bank-decorrelating swizzle, baked into
// the global layout so global_load_lds's contiguous dest reproduces it.
__global__ __launch_bounds__(256)
void build_x_kernel(const int* __restrict__ ids,
                    const float* __restrict__ embed,
                    uint16_t* __restrict__ xbf) {
    int i    = blockIdx.x * 256 + threadIdx.x;   // float4 index (2,097,152)
    int rowi = i >> 6;                           // b*128 + t
    int c4   = i & 63;                           // float4 within 256-elem row
    int b    = rowi >> 7;
    int id   = ids[rowi];
    float4 v = ((const float4*)(embed + (size_t)id * kInit))[c4];
    uint16_t q[4] = { f2bf(v.x), f2bf(v.y), f2bf(v.z), f2bf(v.w) };
    int chunk = c4 >> 1, half = c4 & 1;          // 16B chunk 0..31
    int slot  = chunk ^ (b & 15);
    ((short4v*)xbf)[(size_t)rowi * 64 + slot * 2 + half] = *(short4v*)q;
}

// ---- kernel 2: the scan ----
__global__ __launch_bounds__(kThreads)
__attribute__((amdgpu_waves_per_eu(1, 2)))
void tree_lstm_kernel(const uint16_t* __restrict__ wbf,
                      const uint16_t* __restrict__ xbf,
                      const float* __restrict__ whx_b,
                      const float* __restrict__ init_state,
                      const float* __restrict__ final_w,
                      const float* __restrict__ final_b,
                      const int* __restrict__ ids,
                      float* __restrict__ out)
{
    // swizzled: element (row, col) lives at [row][ ((col>>3)^row)*8 + (col&7) ]
    __shared__ alignas(16) uint16_t hb[2][kRows][kState];   // 8 KB  (h)
    __shared__ alignas(16) uint16_t xb[2][kRows][kInit];    // 16 KB (x: rh|rc)
    __shared__ float partial[kRows][3][4];
    // >80 KiB total => exactly 1 workgroup/CU (proven to materialize in R6).
    __shared__ float lds_force_pad[14400];                  // 57.6 KiB

    const int tid  = threadIdx.x;
    const int w    = tid >> 6;        // wave 0..7 -> j-slice [16w,16w+16)
    const int lane = tid & 63;
    const int l15  = lane & 15;       // batch row (MFMA D col / B col)
    const int quad = lane >> 4;       // 0..3
    const int b0   = blockIdx.x * kRows;
    const int j0   = w * 16 + quad * 4;   // 4 consecutive j (MFMA D rows)
    const int r2   = lane >> 5;       // gload: row pair half (0/1)
    const int sl   = lane & 31;       // gload: 16B slot within row

    if (__builtin_expect(ids[0] < 0, 0)) {      // never true; keeps pad alive
        volatile float* vp = lds_force_pad;
        vp[tid] = (float)tid;
        float v = vp[(tid * 7) & 14399];
        if (v < -1.0e30f) out[0] = v;
    }

    // bias in registers (20 VGPRs; loaded before wf so no pressure spike)
    floatx4 bias4[5];
#pragma unroll
    for (int g = 0; g < 5; ++g)
        bias4[g] = *(const floatx4*)(whx_b + g * 128 + j0);

    // register-resident A-frags, loaded directly as bf16 (R8: no spill)
    short8 wf[5][8];
#pragma unroll
    for (int g = 0; g < 5; ++g) {
        const uint16_t* wrow = wbf + (size_t)(g * 128 + w * 16 + l15) * kInit;
#pragma unroll
        for (int kk = 0; kk < 8; ++kk)
            wf[g][kk] = *(const short8*)(wrow + kk * 32 + quad * 8);
    }

    // h0 (bf16, swizzled into hb[0]) and c0 (fp32 regs), broadcast over batch
    const int ch2   = 2 * w + (quad >> 1);        // h chunk of j0
    const int hoff  = (ch2 ^ l15) * 8 + (quad & 1) * 4;  // elem offset in row
    float c_reg[4];
    {
        uint16_t h0[4];
#pragma unroll
        for (int r = 0; r < 4; ++r) {
            h0[r]    = f2bf(init_state[j0 + r]);
            c_reg[r] = init_state[128 + j0 + r];
        }
        *(short4v*)&hb[0][l15][hoff] = *(short4v*)h0;
    }

    // preload x(:,0) -> xb[0]: ONE gload/wave covers rows 2w,2w+1 (1024 B)
    gload_lds16(xbf + ((size_t)(b0 + 2 * w + r2) * kL) * kInit + sl * 8,
                &xb[0][2 * w][0]);
    __syncthreads();   // drains gload (vmcnt 0); h0 visible

    const float K1 = 1.442695041f;   // log2(e)
    const float K2 = 2.885390082f;   // 2*log2(e)
    const int   cx2  = 16 + 2 * w + (quad >> 1);  // right_c chunk of j0
    const int   rcof = (quad & 1) * 4;

#pragma unroll 1
    for (int t = 0; t < kL; ++t) {
        const int cur = t & 1, nxt = cur ^ 1;

        // prefetch x(:, t+1) -> xb[nxt] (linear stream; zero VGPR cost)
        const int tn = (t + 1 < kL) ? t + 1 : kL - 1;
        gload_lds16(xbf + ((size_t)(b0 + 2 * w + r2) * kL + tn) * kInit + sl * 8,
                    &xb[nxt][2 * w][0]);

        floatx4 acc[5];
#pragma unroll
        for (int g = 0; g < 5; ++g) acc[g] = bias4[g];

        // K-loop: h part (k 0..127) from hb, x part (k 128..255) from xb
        const uint16_t* hrow = &hb[cur][l15][0];
        const uint16_t* xrow = &xb[cur][l15][0];
#pragma unroll
        for (int kk = 0; kk < 4; ++kk) {
            short8 xf = *(const short8*)(hrow + ((kk * 4 + quad) ^ l15) * 8);
#pragma unroll
            for (int g = 0; g < 5; ++g)
                acc[g] = __builtin_amdgcn_mfma_f32_16x16x32_bf16(wf[g][kk], xf, acc[g], 0, 0, 0);
        }
#pragma unroll
        for (int kk = 4; kk < 8; ++kk) {
            short8 xf = *(const short8*)(xrow + (((kk - 4) * 4 + quad) ^ l15) * 8);
#pragma unroll
            for (int g = 0; g < 5; ++g)
                acc[g] = __builtin_amdgcn_mfma_f32_16x16x32_bf16(wf[g][kk], xf, acc[g], 0, 0, 0);
        }

        // gates: lane owns (b=l15, j=j0..j0+3)
        short4v rcv = *(const short4v*)&xb[cur][l15][(cx2 ^ l15) * 8 + rcof];
        uint16_t hv[4];
#pragma unroll
        for (int r = 0; r < 4; ++r) {
            float a  = clampf(acc[0][r], -15.f, 15.f);
            float ii = clampf(acc[1][r], -30.f, 30.f);
            float f1 = clampf(acc[2][r], -30.f, 30.f);
            float f2 = clampf(acc[3][r], -30.f, 30.f);
            float oo = clampf(acc[4][r], -30.f, 30.f);

            float Ea = exp2f(a * K2);                 // e^{2a}
            float Ei = exp2f(-ii * K1);               // e^{-i}
            float P  = (Ea - 1.0f) * __builtin_amdgcn_rcpf((Ea + 1.0f) * (1.0f + Ei));
            float E1 = exp2f(f1 * K1), E2 = exp2f(f2 * K1);
            float lc = c_reg[r], rc = bf2f((uint16_t)rcv[r]);
            float num = E1 * (1.0f + E2) * lc + E2 * (1.0f + E1) * rc;
            float Q  = num * __builtin_amdgcn_rcpf((1.0f + E1) * (1.0f + E2));
            float c  = P + Q;
            c_reg[r] = c;
            float Eo = exp2f(-oo * K1);
            float cc = clampf(c, -15.f, 15.f);
            float Ec = exp2f(cc * K2);
            float h  = (Ec - 1.0f) * __builtin_amdgcn_rcpf((1.0f + Eo) * (Ec + 1.0f));
            hv[r] = f2bf(h);
        }
        *(short4v*)&hb[nxt][l15][hoff] = *(short4v*)hv;

        __syncthreads();   // single barrier: drains gload, publishes h
    }

    // final: out[b][o] = sum_j h[b][j]*final_w[o][j] + final_b[o]
    // final h is in hb[0] (t=127 wrote nxt=0), swizzled
    if (tid < 192) {
        int b = tid / 12, rem = tid % 12;
        int o = rem >> 2, q4 = rem & 3;
        float s = 0.f;
        const float* wrow = final_w + o * kState;
#pragma unroll 8
        for (int j = q4 * 32; j < q4 * 32 + 32; ++j) {
            uint16_t hval = hb[0][b][((j >> 3) ^ b) * 8 + (j & 7)];
            s += bf2f(hval) * wrow[j];
        }
        partial[b][o][q4] = s;
    }
    __syncthreads();
    if (tid < 48) {
        int b = tid / 3, o = tid % 3;
        float s = partial[b][o][0] + partial[b][o][1] +
                  partial[b][o][2] + partial[b][o][3] + final_b[o];
        out[(b0 + b) * 3 + o] = s;
    }
}

extern "C" void kernel_launch(void* const* d_in, const int* in_sizes, int n_in,
                              void* d_out, int out_size, void* d_ws, size_t ws_size,
                              hipStream_t stream) {
    const int*   ids        = (const int*)d_in[0];
    const float* embed      = (const float*)d_in[1];
    const float* whx_w      = (const float*)d_in[2];
    const float* whx_b      = (const float*)d_in[3];
    const float* init_state = (const float*)d_in[4];
    const float* final_w    = (const float*)d_in[5];
    const float* final_b    = (const float*)d_in[6];
    float*       out        = (float*)d_out;
    uint16_t*    wbf        = (uint16_t*)d_ws;          // 320 KiB
    uint16_t*    xbf        = wbf + kWElems;            // 16.8 MiB

    convert_weights_kernel<<<kWElems / 4 / 256, 256, 0, stream>>>(whx_w, wbf);
    build_x_kernel<<<kXRows * 64 / 256, 256, 0, stream>>>(ids, embed, xbf);
    tree_lstm_kernel<<<kBlocks, kThreads, 0, stream>>>(
        wbf, xbf, whx_b, init_state, final_w, final_b, ids, out);
}